// Round 8
// baseline (202.753 us; speedup 1.0000x reference)
//
#include <hip/hip_runtime.h>
#include <hip/hip_bf16.h>

#define NB 4
#define NC 256
#define NHW 4096
#define CPG 8
#define GEPS 1e-6f

typedef __hip_bfloat16 bf16;
typedef __attribute__((ext_vector_type(8))) short bf16x8;
typedef __attribute__((ext_vector_type(4))) float f32x4;
typedef __attribute__((ext_vector_type(8))) unsigned short u16x8;

#define MFMA16(A,B,C) __builtin_amdgcn_mfma_f32_16x16x32_bf16(A,B,C,0,0,0)

typedef __attribute__((address_space(1))) const unsigned int as1_uint;
typedef __attribute__((address_space(3))) unsigned int as3_uint;
__device__ __forceinline__ void gload_lds16(const void* g, void* l){
  __builtin_amdgcn_global_load_lds((as1_uint*)g, (as3_uint*)l, 16, 0, 0);
}

__device__ __forceinline__ float u2f(unsigned short u){
  union { unsigned u32; float f; } w; w.u32 = ((unsigned)u) << 16; return w.f;
}
__device__ __forceinline__ bf16 f2b(float v){ return __float2bfloat16(v); }
__device__ __forceinline__ unsigned short f2bu(float v){
  union { bf16 h; unsigned short u; } w; w.h = __float2bfloat16(v); return w.u;
}
__device__ __forceinline__ unsigned pk2(float lo, float hi){
  return (unsigned)f2bu(lo) | ((unsigned)f2bu(hi) << 16);
}
// raw v_exp_f32 (2^x), no OCML denormal wrapper (exp2f regressed: +5 VALU/val)
__device__ __forceinline__ float fexp2(float x){ return __builtin_amdgcn_exp2f(x); }

// q-scale: C^-0.5 (=1/16) with log2(e) folded so flash can use native exp2
#define QSCALE 0.09016994374947424f   // 0.0625 * 1.4426950408889634

// ---------------- GroupNorm partial stats (4-way split) + weight prep ----------------
// blocks 0..511: partial {sum, sumsq} for (group bg, quarter q) -> full-GPU x read
// blocks 512..1535: weight prep fp32 -> bf16 (+q scale fold)
__global__ __launch_bounds__(256)
void gn_stats_wprep_kernel(const float* __restrict__ x, float* __restrict__ partial,
                           const float* __restrict__ wq, const float* __restrict__ wk,
                           const float* __restrict__ wv, const float* __restrict__ wp,
                           const float* __restrict__ bq, const float* __restrict__ bk,
                           const float* __restrict__ bv,
                           bf16* __restrict__ wqkv, bf16* __restrict__ wpb,
                           float* __restrict__ bqs){
  if(blockIdx.x >= 512){
    int i = (blockIdx.x - 512) * 256 + threadIdx.x;     // 262144 threads
    if(i < 196608){
      float v;
      if(i < 65536)       v = wq[i] * QSCALE;
      else if(i < 131072) v = wk[i - 65536];
      else                v = wv[i - 131072];
      wqkv[i] = f2b(v);
    } else {
      int j = i - 196608;                               // < 65536
      wpb[j] = f2b(wp[j]);
    }
    if(i < 768) bqs[i] = (i < 256) ? bq[i] * QSCALE : (i < 512 ? bk[i - 256] : bv[i - 512]);
    return;
  }
  const int bg = blockIdx.x >> 2, qq = blockIdx.x & 3;
  const float* p = x + (size_t)bg * (CPG * NHW) + qq * 8192;
  float s = 0.f, s2 = 0.f;
  for(int i = threadIdx.x * 4; i < 8192; i += 1024){
    float4 v = *(const float4*)(p + i);
    s  += v.x + v.y + v.z + v.w;
    s2 += v.x*v.x + v.y*v.y + v.z*v.z + v.w*v.w;
  }
  __shared__ float red[256];
  red[threadIdx.x] = s; __syncthreads();
  for(int t = 128; t > 0; t >>= 1){
    if(threadIdx.x < t) red[threadIdx.x] += red[threadIdx.x + t];
    __syncthreads();
  }
  float sum = red[0]; __syncthreads();
  red[threadIdx.x] = s2; __syncthreads();
  for(int t = 128; t > 0; t >>= 1){
    if(threadIdx.x < t) red[threadIdx.x] += red[threadIdx.x + t];
    __syncthreads();
  }
  if(threadIdx.x == 0){
    partial[blockIdx.x * 2]     = sum;
    partial[blockIdx.x * 2 + 1] = red[0];
  }
}

// ---------------- GN apply + transpose: xt[b][n][c] = GN(x)[b][c][n], bf16 ----------------
// folds the 4 stat-partials per group (mean/rsqrt computed per-thread, cheap)
__global__ __launch_bounds__(256)
void gn_prep_kernel(const float* __restrict__ x, const float* __restrict__ partial,
                    const float* __restrict__ gsc, const float* __restrict__ gbi,
                    bf16* __restrict__ xt){
  const int b = blockIdx.z, cB = blockIdx.y * 64, nB = blockIdx.x * 64;
  __shared__ unsigned short Tt[64][80];
  const int tid = threadIdx.x;
  const float* xb = x + ((size_t)(b * NC + cB)) * NHW + nB;
  const float inv_n = 1.f / (float)(CPG * NHW);
  #pragma unroll
  for(int pass = 0; pass < 4; pass++){
    int c_loc = (tid >> 4) + pass * 16;
    int n0 = (tid & 15) * 4;
    float4 v = *(const float4*)(xb + (size_t)c_loc * NHW + n0);
    int c_abs = cB + c_loc, bg = b * 32 + (c_abs >> 3);
    const float* pp = partial + bg * 8;
    float s  = pp[0] + pp[2] + pp[4] + pp[6];
    float s2 = pp[1] + pp[3] + pp[5] + pp[7];
    float mean = s * inv_n;
    float var = s2 * inv_n - mean * mean;
    if(var < 0.f) var = 0.f;
    float rstd = rsqrtf(var + GEPS);
    float a = rstd * gsc[c_abs];
    float d = gbi[c_abs] - mean * a;
    Tt[n0 + 0][c_loc] = f2bu(v.x * a + d);
    Tt[n0 + 1][c_loc] = f2bu(v.y * a + d);
    Tt[n0 + 2][c_loc] = f2bu(v.z * a + d);
    Tt[n0 + 3][c_loc] = f2bu(v.w * a + d);
  }
  __syncthreads();
  int n_loc = tid >> 2, cq = (tid & 3) * 16;
  u16x8 w0 = *(const u16x8*)&Tt[n_loc][cq];
  u16x8 w1 = *(const u16x8*)&Tt[n_loc][cq + 8];
  unsigned short* dst = (unsigned short*)xt + ((size_t)(b * NHW + nB + n_loc)) * NC + cB + cq;
  *(u16x8*)dst = w0;
  *(u16x8*)(dst + 8) = w1;
}

// ---------------- MFMA GEMM (qkv): D[o][n] = W[o][:]·Bm[n][:] + bias[o] ----------------
// oB<256 -> qo [n][C]; <512 -> ko [n][C]; else vo [b][c][n]  (bf16)
// XCD swizzle: cluster consecutive nB-tiles on one XCD so each XCD's B-matrix
// working set L2-fits. Tt halved (two wy-passes) -> LDS 49.4 KB; with
// __launch_bounds__(256,3) this gives 3 blocks/CU -> 768 blocks in one round.
__global__ __launch_bounds__(256, 3)
void gemm_kernel(const bf16* __restrict__ Wb, const bf16* __restrict__ Bm,
                 const float* __restrict__ bias,
                 bf16* __restrict__ qo, bf16* __restrict__ ko, bf16* __restrict__ vo){
  // relabel: lin -> (xcd, idx); nB from xcd*gx8 + idx%gx8, oB from idx/gx8
  const int lin = blockIdx.x + gridDim.x * blockIdx.y;
  const int gx8 = gridDim.x >> 3;                 // nB tiles per XCD (=16)
  const int xcd = lin & 7, idx = lin >> 3;
  const int nB = (xcd * gx8 + (idx & (gx8 - 1))) * 128;
  const int oB = (idx / gx8) * 128;
  const int tid = threadIdx.x;
  const int wave = tid >> 6, lane = tid & 63;
  const int l15 = lane & 15, quad = lane >> 4;
  const int wx = wave & 1, wy = wave >> 1;

  __shared__ __align__(16) unsigned short Ast[2][512 * 8];
  __shared__ __align__(16) unsigned short Bst[2][512 * 8];
  __shared__ __align__(16) unsigned short Tt[64 * 136];

  const short* Wp = (const short*)Wb;
  const short* Bp = (const short*)Bm;

  f32x4 acc[4][4];
  #pragma unroll
  for(int mi = 0; mi < 4; mi++)
    #pragma unroll
    for(int ni = 0; ni < 4; ni++) acc[mi][ni] = (f32x4){0.f, 0.f, 0.f, 0.f};

  // prologue stage k0 = 0 into buf 0
  #pragma unroll
  for(int t = 0; t < 2; t++){
    int qn0 = (wave * 2 + t) * 64, qn = qn0 + lane;
    int o = qn >> 2, slot = qn & 3;
    gload_lds16(Wp + (size_t)(oB + o) * NC + ((slot ^ ((o >> 1) & 3)) * 8), &Ast[0][qn0 * 8]);
  }
  #pragma unroll
  for(int t = 0; t < 2; t++){
    int qn0 = (wave * 2 + t) * 64, qn = qn0 + lane;
    int n = qn >> 2, slot = qn & 3;
    gload_lds16(Bp + (size_t)(nB + n) * NC + ((slot ^ ((n >> 1) & 3)) * 8), &Bst[0][qn0 * 8]);
  }

  for(int kt = 0; kt < 8; kt++){
    __syncthreads();
    const int p = kt & 1;
    if(kt < 7){
      const int k0 = (kt + 1) * 32;
      #pragma unroll
      for(int t = 0; t < 2; t++){
        int qn0 = (wave * 2 + t) * 64, qn = qn0 + lane;
        int o = qn >> 2, slot = qn & 3;
        gload_lds16(Wp + (size_t)(oB + o) * NC + k0 + ((slot ^ ((o >> 1) & 3)) * 8), &Ast[p ^ 1][qn0 * 8]);
      }
      #pragma unroll
      for(int t = 0; t < 2; t++){
        int qn0 = (wave * 2 + t) * 64, qn = qn0 + lane;
        int n = qn >> 2, slot = qn & 3;
        gload_lds16(Bp + (size_t)(nB + n) * NC + k0 + ((slot ^ ((n >> 1) & 3)) * 8), &Bst[p ^ 1][qn0 * 8]);
      }
    }
    bf16x8 Af[4], Bf[4];
    #pragma unroll
    for(int mi = 0; mi < 4; mi++){
      int o = wx * 64 + mi * 16 + l15;
      Af[mi] = *(const bf16x8*)&Ast[p][(o * 4 + (quad ^ ((o >> 1) & 3))) * 8];
    }
    #pragma unroll
    for(int ni = 0; ni < 4; ni++){
      int n = wy * 64 + ni * 16 + l15;
      Bf[ni] = *(const bf16x8*)&Bst[p][(n * 4 + (quad ^ ((n >> 1) & 3))) * 8];
    }
    __builtin_amdgcn_s_setprio(1);
    #pragma unroll
    for(int mi = 0; mi < 4; mi++)
      #pragma unroll
      for(int ni = 0; ni < 4; ni++)
        acc[mi][ni] = MFMA16(Af[mi], Bf[ni], acc[mi][ni]);
    __builtin_amdgcn_s_setprio(0);
  }

  float bi[4][4];
  #pragma unroll
  for(int mi = 0; mi < 4; mi++)
    #pragma unroll
    for(int r = 0; r < 4; r++)
      bi[mi][r] = bias[oB + wx * 64 + mi * 16 + quad * 4 + r];

  if(oB >= 512){
    #pragma unroll
    for(int mi = 0; mi < 4; mi++){
      #pragma unroll
      for(int ni = 0; ni < 4; ni++){
        int na = nB + wy * 64 + ni * 16 + l15;
        #pragma unroll
        for(int r = 0; r < 4; r++){
          int c = oB - 512 + wx * 64 + mi * 16 + quad * 4 + r;
          vo[((size_t)(na >> 12) * NC + c) * NHW + (na & 4095)] = f2b(acc[mi][ni][r] + bi[mi][r]);
        }
      }
    }
  } else {
    // q/k: transpose through half-size Tt in two wy-passes, write [n][C]
    bf16* dst = (oB < 256) ? qo : ko;
    const int oc0 = oB & 255;      // 0/128 for q, 256/384 -> 0/128 for k
    #pragma unroll
    for(int hp = 0; hp < 2; hp++){
      if(hp) __syncthreads();      // protect Tt reuse across passes
      if(wy == hp){
        #pragma unroll
        for(int mi = 0; mi < 4; mi++){
          int ob = wx * 64 + mi * 16 + quad * 4;
          #pragma unroll
          for(int ni = 0; ni < 4; ni++){
            int nl = ni * 16 + l15;          // 0..63
            ushort4 pk;
            pk.x = f2bu(acc[mi][ni][0] + bi[mi][0]);
            pk.y = f2bu(acc[mi][ni][1] + bi[mi][1]);
            pk.z = f2bu(acc[mi][ni][2] + bi[mi][2]);
            pk.w = f2bu(acc[mi][ni][3] + bi[mi][3]);
            *(ushort4*)&Tt[nl * 136 + ob] = pk;
          }
        }
      }
      __syncthreads();
      int row = tid >> 2, cq = (tid & 3) * 32;
      unsigned short* gp = (unsigned short*)dst + (size_t)(nB + hp * 64 + row) * NC + oc0 + cq;
      #pragma unroll
      for(int j = 0; j < 4; j++)
        *(u16x8*)(gp + j * 8) = *(const u16x8*)&Tt[row * 136 + cq + j * 8];
    }
  }
}

// ---------------- proj GEMM with fused combine ----------------
// Tile 64o x 64n, grid (256,4) = 1024 blocks -> 4 blocks/CU, 16 waves/CU
// (R7: proj is latency-bound on its staging+fp32 epilogue; 2x the independent
// chains + 2x waves. acc[2][2]=16 AGPR, LDS 16 KB -> trivially fits (256,4)).
// B-row n = attn[n][:] = (Σ_h Opart_h[n][:]) * inv_l[n], combined in-register
// during staging; inv_l computed once in the prologue.
__global__ __launch_bounds__(256, 4)
void proj_gemm_kernel(const bf16* __restrict__ Wb, const bf16* __restrict__ Opart,
                      const float* __restrict__ lpart, const float* __restrict__ bias,
                      float* __restrict__ fo, const float* __restrict__ xres){
  const int lin = blockIdx.x + gridDim.x * blockIdx.y;
  const int gx8 = gridDim.x >> 3;                 // 32 nB-tiles (of 64) per XCD
  const int xcd = lin & 7, idx = lin >> 3;
  const int nB = (xcd * gx8 + (idx & (gx8 - 1))) * 64;
  const int oB = (idx / gx8) * 64;                // 0/64/128/192
  const int tid = threadIdx.x;
  const int wave = tid >> 6, lane = tid & 63;
  const int l15 = lane & 15, quad = lane >> 4;
  const int wx = wave & 1, wy = wave >> 1;        // 2x2 wave grid, 32o x 32n each
  const int HS = NB * NHW;                        // 16384 rows per quarter
  const size_t QSTRIDE = (size_t)HS * NC;         // elements per quarter

  __shared__ __align__(16) unsigned short Ast[2][256 * 8];
  __shared__ __align__(16) unsigned short Bst[2][256 * 8];

  const short* Wp = (const short*)Wb;
  const unsigned short* Op = (const unsigned short*)Opart;

  // per-lane fixed staging coords (one 256-lane slot covers each 64x32 tile)
  const int qn = tid;
  const int bn = qn >> 2, bsl = qn & 3;
  const int coff = (bsl ^ ((bn >> 1) & 3)) * 8;
  const int ng = nB + bn;
  const float lsum = lpart[ng] + lpart[HS + ng] + lpart[2 * HS + ng] + lpart[3 * HS + ng];
  const float inv = 1.f / lsum;
  const size_t base = (size_t)ng * NC + coff;
  const size_t wbase = (size_t)(oB + bn) * NC + coff;   // A staging: row o=bn

  f32x4 acc[2][2];
  #pragma unroll
  for(int mi = 0; mi < 2; mi++)
    #pragma unroll
    for(int ni = 0; ni < 2; ni++) acc[mi][ni] = (f32x4){0.f, 0.f, 0.f, 0.f};

  // prologue: stage kt=0 into buf 0
  gload_lds16(Wp + wbase, &Ast[0][qn * 8]);
  {
    u16x8 a0 = *(const u16x8*)(Op + base);
    u16x8 a1 = *(const u16x8*)(Op + base + QSTRIDE);
    u16x8 a2 = *(const u16x8*)(Op + base + 2 * QSTRIDE);
    u16x8 a3 = *(const u16x8*)(Op + base + 3 * QSTRIDE);
    u16x8 o;
    #pragma unroll
    for(int e = 0; e < 8; e++)
      o[e] = f2bu((u2f(a0[e]) + u2f(a1[e]) + u2f(a2[e]) + u2f(a3[e])) * inv);
    *(u16x8*)&Bst[0][qn * 8] = o;
  }

  for(int kt = 0; kt < 8; kt++){
    __syncthreads();
    const int p = kt & 1;
    if(kt < 7){
      const int k0 = (kt + 1) * 32;
      gload_lds16(Wp + wbase + k0, &Ast[p ^ 1][qn * 8]);
      u16x8 a0 = *(const u16x8*)(Op + base + k0);
      u16x8 a1 = *(const u16x8*)(Op + base + k0 + QSTRIDE);
      u16x8 a2 = *(const u16x8*)(Op + base + k0 + 2 * QSTRIDE);
      u16x8 a3 = *(const u16x8*)(Op + base + k0 + 3 * QSTRIDE);
      u16x8 o;
      #pragma unroll
      for(int e = 0; e < 8; e++)
        o[e] = f2bu((u2f(a0[e]) + u2f(a1[e]) + u2f(a2[e]) + u2f(a3[e])) * inv);
      *(u16x8*)&Bst[p ^ 1][qn * 8] = o;
    }
    bf16x8 Af[2], Bf[2];
    #pragma unroll
    for(int mi = 0; mi < 2; mi++){
      int o = wx * 32 + mi * 16 + l15;
      Af[mi] = *(const bf16x8*)&Ast[p][(o * 4 + (quad ^ ((o >> 1) & 3))) * 8];
    }
    #pragma unroll
    for(int ni = 0; ni < 2; ni++){
      int n = wy * 32 + ni * 16 + l15;
      Bf[ni] = *(const bf16x8*)&Bst[p][(n * 4 + (quad ^ ((n >> 1) & 3))) * 8];
    }
    __builtin_amdgcn_s_setprio(1);
    #pragma unroll
    for(int mi = 0; mi < 2; mi++)
      #pragma unroll
      for(int ni = 0; ni < 2; ni++)
        acc[mi][ni] = MFMA16(Af[mi], Bf[ni], acc[mi][ni]);
    __builtin_amdgcn_s_setprio(0);
  }

  float bi[2][4];
  #pragma unroll
  for(int mi = 0; mi < 2; mi++)
    #pragma unroll
    for(int r = 0; r < 4; r++)
      bi[mi][r] = bias[oB + wx * 32 + mi * 16 + quad * 4 + r];

  #pragma unroll
  for(int mi = 0; mi < 2; mi++){
    #pragma unroll
    for(int ni = 0; ni < 2; ni++){
      int na = nB + wy * 32 + ni * 16 + l15;
      #pragma unroll
      for(int r = 0; r < 4; r++){
        int c = oB + wx * 32 + mi * 16 + quad * 4 + r;
        size_t idx2 = ((size_t)(na >> 12) * NC + c) * NHW + (na & 4095);
        fo[idx2] = acc[mi][ni][r] + bi[mi][r] + xres[idx2];
      }
    }
  }
}

// ---------------- MFMA flash: i=32/wave, jsplit=4, no-max softmax ----------------
// q,kt: [B][n][C] (q pre-scaled C^-0.5 * log2e)  v: [B][C][n]
// S in log2-domain, P = v_exp_f32(S) via __builtin_amdgcn_exp2f (raw instr;
// library exp2f added a denormal-handling wrapper that cost +7 µs in R6).
// XCD swizzle: 2 (b,h) pairs per XCD -> K/V working set 2MB, L2-fits.
// P redistribution (S^T D-layout -> PV A-frag) fully in-register via
// permlane32_swap + permlane16_swap (see R1 notes).
__global__ __launch_bounds__(256, 2)
void flash_mfma4_kernel(const bf16* __restrict__ qg, const bf16* __restrict__ ktg,
                        const bf16* __restrict__ vg, bf16* __restrict__ Opart,
                        float* __restrict__ lpart){
  const int lin = blockIdx.x + 32 * (blockIdx.y + 4 * blockIdx.z);
  const int xcd = lin & 7, slot = lin >> 3;       // 512 = 8 XCDs x 64 slots
  const int bh = xcd * 2 + (slot >> 5);           // 2 (b,h) pairs per XCD
  const int b = bh & 3, h = bh >> 2;
  const int i0 = (slot & 31) * 128;
  const int tid = threadIdx.x;
  const int wave = tid >> 6, lane = tid & 63;
  const int l15 = lane & 15, quad = lane >> 4;

  __shared__ __align__(16) unsigned short Kt[2][1024 * 8];   // 2 x 16 KB
  __shared__ __align__(16) unsigned short Vt[2][1024 * 8];   // 2 x 16 KB

  bf16x8 Qf[2][8];
  #pragma unroll
  for(int ist = 0; ist < 2; ist++){
    const short* qp = (const short*)qg +
        ((size_t)b * NHW + i0 + wave * 32 + ist * 16 + l15) * NC + quad * 8;
    #pragma unroll
    for(int ks = 0; ks < 8; ks++) Qf[ist][ks] = *(const bf16x8*)(qp + ks * 32);
  }

  const short* kb = (const short*)ktg + ((size_t)b * NHW + h * 1024) * NC;
  const short* vb = (const short*)vg + (size_t)b * NC * NHW + h * 1024;

  f32x4 O[2][16];
  #pragma unroll
  for(int ist = 0; ist < 2; ist++)
    #pragma unroll
    for(int ct = 0; ct < 16; ct++) O[ist][ct] = (f32x4){0.f, 0.f, 0.f, 0.f};
  float lr0 = 0.f, lr1 = 0.f;

  // prologue: stage tile 0
  #pragma unroll
  for(int t = 0; t < 4; t++){
    int qn0 = (wave * 4 + t) * 64, qn = qn0 + lane;
    int j = qn >> 5, slot2 = qn & 31;
    gload_lds16(kb + (size_t)j * NC + ((slot2 ^ (j & 7)) * 8), &Kt[0][qn0 * 8]);
  }
  #pragma unroll
  for(int t = 0; t < 4; t++){
    int qn0 = (wave * 4 + t) * 64, qn = qn0 + lane;
    int c = qn >> 2, slot2 = qn & 3;
    gload_lds16(vb + (size_t)c * NHW + ((slot2 ^ ((c >> 1) & 3)) * 8), &Vt[0][qn0 * 8]);
  }

  for(int jt = 0; jt < 32; jt++){
    __syncthreads();
    const int p = jt & 1;
    if(jt < 31){
      const int j0n = (jt + 1) * 32;
      #pragma unroll
      for(int t = 0; t < 4; t++){
        int qn0 = (wave * 4 + t) * 64, qn = qn0 + lane;
        int j = qn >> 5, slot2 = qn & 31;
        gload_lds16(kb + (size_t)(j0n + j) * NC + ((slot2 ^ (j & 7)) * 8), &Kt[p ^ 1][qn0 * 8]);
      }
      #pragma unroll
      for(int t = 0; t < 4; t++){
        int qn0 = (wave * 4 + t) * 64, qn = qn0 + lane;
        int c = qn >> 2, slot2 = qn & 3;
        gload_lds16(vb + (size_t)c * NHW + j0n + ((slot2 ^ ((c >> 1) & 3)) * 8), &Vt[p ^ 1][qn0 * 8]);
      }
    }
    // ---- S^T = K·Q^T for both i-subtiles (K-frag read once) ----
    f32x4 S[2][2];
    __builtin_amdgcn_s_setprio(1);
    #pragma unroll
    for(int st = 0; st < 2; st++){
      S[st][0] = (f32x4){0.f, 0.f, 0.f, 0.f};
      S[st][1] = (f32x4){0.f, 0.f, 0.f, 0.f};
      const int j = st * 16 + l15;
      const unsigned short* kr = &Kt[p][(size_t)j * 256];
      #pragma unroll
      for(int ks = 0; ks < 8; ks++){
        int slot2 = (ks * 4 + quad) ^ (j & 7);
        bf16x8 kf = *(const bf16x8*)&kr[slot2 * 8];
        S[st][0] = MFMA16(kf, Qf[0][ks], S[st][0]);
        S[st][1] = MFMA16(kf, Qf[1][ks], S[st][1]);
      }
    }
    __builtin_amdgcn_s_setprio(0);
    // ---- P = exp2(S); build PV A-frags fully in-register ----
    bf16x8 Pf[2];
    #pragma unroll
    for(int ist = 0; ist < 2; ist++){
      float p0 = fexp2(S[0][ist][0]), p1 = fexp2(S[0][ist][1]);
      float p2 = fexp2(S[0][ist][2]), p3 = fexp2(S[0][ist][3]);
      float p4 = fexp2(S[1][ist][0]), p5 = fexp2(S[1][ist][1]);
      float p6 = fexp2(S[1][ist][2]), p7 = fexp2(S[1][ist][3]);
      float sm = ((p0 + p1) + (p2 + p3)) + ((p4 + p5) + (p6 + p7));
      if(ist == 0) lr0 += sm; else lr1 += sm;
      unsigned A0 = pk2(p0, p1), A1 = pk2(p2, p3);
      unsigned B0 = pk2(p4, p5), B1 = pk2(p6, p7);
      auto s0 = __builtin_amdgcn_permlane32_swap(A0, B0, false, false);
      auto t0 = __builtin_amdgcn_permlane16_swap(s0[0], s0[1], false, false);
      auto s1 = __builtin_amdgcn_permlane32_swap(A1, B1, false, false);
      auto t1 = __builtin_amdgcn_permlane16_swap(s1[0], s1[1], false, false);
      union { unsigned u[4]; bf16x8 v; } w;
      w.u[0] = t0[0]; w.u[1] = t1[0]; w.u[2] = t0[1]; w.u[3] = t1[1];
      Pf[ist] = w.v;
    }
    // ---- O += P·V^T (V-frag read once, both i-subtiles) ----
    __builtin_amdgcn_s_setprio(1);
    #pragma unroll
    for(int ct = 0; ct < 16; ct++){
      int c = ct * 16 + l15;
      bf16x8 vf = *(const bf16x8*)&Vt[p][(c * 4 + (quad ^ ((c >> 1) & 3))) * 8];
      O[0][ct] = MFMA16(Pf[0], vf, O[0][ct]);
      O[1][ct] = MFMA16(Pf[1], vf, O[1][ct]);
    }
    __builtin_amdgcn_s_setprio(0);
  }

  lr0 += __shfl_xor(lr0, 16); lr0 += __shfl_xor(lr0, 32);
  lr1 += __shfl_xor(lr1, 16); lr1 += __shfl_xor(lr1, 32);

  const size_t hb = (size_t)(h * NB + b) * NHW;
  #pragma unroll
  for(int ist = 0; ist < 2; ist++){
    #pragma unroll
    for(int r = 0; r < 4; r++){
      int i = i0 + wave * 32 + ist * 16 + quad * 4 + r;
      unsigned short* od = (unsigned short*)Opart + (hb + i) * NC + l15;
      #pragma unroll
      for(int ct = 0; ct < 16; ct++) od[ct * 16] = f2bu(O[ist][ct][r]);
    }
  }
  if(lane < 16){
    lpart[hb + i0 + wave * 32 + l15]      = lr0;
    lpart[hb + i0 + wave * 32 + 16 + l15] = lr1;
  }
}

extern "C" void kernel_launch(void* const* d_in, const int* in_sizes, int n_in,
                              void* d_out, int out_size, void* d_ws, size_t ws_size,
                              hipStream_t stream){
  (void)in_sizes; (void)n_in; (void)out_size; (void)ws_size;
  const float* x        = (const float*)d_in[0];
  const float* gn_scale = (const float*)d_in[1];
  const float* gn_bias  = (const float*)d_in[2];
  const float* wq = (const float*)d_in[3];  const float* bq = (const float*)d_in[4];
  const float* wk = (const float*)d_in[5];  const float* bk = (const float*)d_in[6];
  const float* wv = (const float*)d_in[7];  const float* bv = (const float*)d_in[8];
  const float* wp = (const float*)d_in[9];  const float* bp = (const float*)d_in[10];
  float* out = (float*)d_out;

  char* ws = (char*)d_ws;
  const size_t MB = 1048576;
  float* partial = (float*)ws;                       // 4 KB (128 groups x 4 quarters x 2)
  float* bqs   = (float*)(ws + 4096);                // 3 KB
  bf16* wqkv   = (bf16*)(ws + 8192);                 // 384 KB
  bf16* wpb    = (bf16*)(ws + 8192 + 393216);        // 128 KB
  bf16* xt     = (bf16*)(ws + 1 * MB);               // 8 MB (region reserved 32 MB)
  bf16* Opart  = xt;                                 // alias: xt dead after qkv gemm
  bf16* q      = (bf16*)(ws + 33 * MB);              // 8 MB
  bf16* k      = (bf16*)(ws + 41 * MB);              // 8 MB
  bf16* v      = (bf16*)(ws + 49 * MB);              // 8 MB
  float* lpart = (float*)(ws + 57 * MB);             // 256 KB

  gn_stats_wprep_kernel<<<1536, 256, 0, stream>>>(
      x, partial, wq, wk, wv, wp, bq, bk, bv, wqkv, wpb, bqs);
  gn_prep_kernel<<<dim3(64, 4, NB), 256, 0, stream>>>(x, partial, gn_scale, gn_bias, xt);

  gemm_kernel<<<dim3(128, 6), 256, 0, stream>>>(
      wqkv, xt, bqs, q, k, v);

  flash_mfma4_kernel<<<dim3(32, NB, 4), 256, 0, stream>>>(q, k, v, Opart, lpart);

  proj_gemm_kernel<<<dim3(256, 4), 256, 0, stream>>>(
      wpb, Opart, lpart, bp, out, x);
}

// Round 9
// 200.514 us; speedup vs baseline: 1.0112x; 1.0112x over previous
//
#include <hip/hip_runtime.h>
#include <hip/hip_bf16.h>

#define NB 4
#define NC 256
#define NHW 4096
#define CPG 8
#define GEPS 1e-6f

typedef __hip_bfloat16 bf16;
typedef __attribute__((ext_vector_type(8))) short bf16x8;
typedef __attribute__((ext_vector_type(4))) float f32x4;
typedef __attribute__((ext_vector_type(8))) unsigned short u16x8;

#define MFMA16(A,B,C) __builtin_amdgcn_mfma_f32_16x16x32_bf16(A,B,C,0,0,0)

typedef __attribute__((address_space(1))) const unsigned int as1_uint;
typedef __attribute__((address_space(3))) unsigned int as3_uint;
__device__ __forceinline__ void gload_lds16(const void* g, void* l){
  __builtin_amdgcn_global_load_lds((as1_uint*)g, (as3_uint*)l, 16, 0, 0);
}

__device__ __forceinline__ float u2f(unsigned short u){
  union { unsigned u32; float f; } w; w.u32 = ((unsigned)u) << 16; return w.f;
}
__device__ __forceinline__ bf16 f2b(float v){ return __float2bfloat16(v); }
__device__ __forceinline__ unsigned short f2bu(float v){
  union { bf16 h; unsigned short u; } w; w.h = __float2bfloat16(v); return w.u;
}
__device__ __forceinline__ unsigned pk2(float lo, float hi){
  return (unsigned)f2bu(lo) | ((unsigned)f2bu(hi) << 16);
}
// raw v_exp_f32 (2^x), no OCML denormal wrapper (exp2f regressed: +5 VALU/val)
__device__ __forceinline__ float fexp2(float x){ return __builtin_amdgcn_exp2f(x); }

// q-scale: C^-0.5 (=1/16) with log2(e) folded so flash can use native exp2
#define QSCALE 0.09016994374947424f   // 0.0625 * 1.4426950408889634

// ---------------- GroupNorm partial stats (4-way split) + weight prep ----------------
// blocks 0..511: partial {sum, sumsq} for (group bg, quarter q) -> full-GPU x read
// blocks 512..1535: weight prep fp32 -> bf16 (+q scale fold)
__global__ __launch_bounds__(256)
void gn_stats_wprep_kernel(const float* __restrict__ x, float* __restrict__ partial,
                           const float* __restrict__ wq, const float* __restrict__ wk,
                           const float* __restrict__ wv, const float* __restrict__ wp,
                           const float* __restrict__ bq, const float* __restrict__ bk,
                           const float* __restrict__ bv,
                           bf16* __restrict__ wqkv, bf16* __restrict__ wpb,
                           float* __restrict__ bqs){
  if(blockIdx.x >= 512){
    int i = (blockIdx.x - 512) * 256 + threadIdx.x;     // 262144 threads
    if(i < 196608){
      float v;
      if(i < 65536)       v = wq[i] * QSCALE;
      else if(i < 131072) v = wk[i - 65536];
      else                v = wv[i - 131072];
      wqkv[i] = f2b(v);
    } else {
      int j = i - 196608;                               // < 65536
      wpb[j] = f2b(wp[j]);
    }
    if(i < 768) bqs[i] = (i < 256) ? bq[i] * QSCALE : (i < 512 ? bk[i - 256] : bv[i - 512]);
    return;
  }
  const int bg = blockIdx.x >> 2, qq = blockIdx.x & 3;
  const float* p = x + (size_t)bg * (CPG * NHW) + qq * 8192;
  float s = 0.f, s2 = 0.f;
  for(int i = threadIdx.x * 4; i < 8192; i += 1024){
    float4 v = *(const float4*)(p + i);
    s  += v.x + v.y + v.z + v.w;
    s2 += v.x*v.x + v.y*v.y + v.z*v.z + v.w*v.w;
  }
  __shared__ float red[256];
  red[threadIdx.x] = s; __syncthreads();
  for(int t = 128; t > 0; t >>= 1){
    if(threadIdx.x < t) red[threadIdx.x] += red[threadIdx.x + t];
    __syncthreads();
  }
  float sum = red[0]; __syncthreads();
  red[threadIdx.x] = s2; __syncthreads();
  for(int t = 128; t > 0; t >>= 1){
    if(threadIdx.x < t) red[threadIdx.x] += red[threadIdx.x + t];
    __syncthreads();
  }
  if(threadIdx.x == 0){
    partial[blockIdx.x * 2]     = sum;
    partial[blockIdx.x * 2 + 1] = red[0];
  }
}

// ---------------- GN apply + transpose: xt[b][n][c] = GN(x)[b][c][n], bf16 ----------------
// folds the 4 stat-partials per group (mean/rsqrt computed per-thread, cheap)
__global__ __launch_bounds__(256)
void gn_prep_kernel(const float* __restrict__ x, const float* __restrict__ partial,
                    const float* __restrict__ gsc, const float* __restrict__ gbi,
                    bf16* __restrict__ xt){
  const int b = blockIdx.z, cB = blockIdx.y * 64, nB = blockIdx.x * 64;
  __shared__ unsigned short Tt[64][80];
  const int tid = threadIdx.x;
  const float* xb = x + ((size_t)(b * NC + cB)) * NHW + nB;
  const float inv_n = 1.f / (float)(CPG * NHW);
  #pragma unroll
  for(int pass = 0; pass < 4; pass++){
    int c_loc = (tid >> 4) + pass * 16;
    int n0 = (tid & 15) * 4;
    float4 v = *(const float4*)(xb + (size_t)c_loc * NHW + n0);
    int c_abs = cB + c_loc, bg = b * 32 + (c_abs >> 3);
    const float* pp = partial + bg * 8;
    float s  = pp[0] + pp[2] + pp[4] + pp[6];
    float s2 = pp[1] + pp[3] + pp[5] + pp[7];
    float mean = s * inv_n;
    float var = s2 * inv_n - mean * mean;
    if(var < 0.f) var = 0.f;
    float rstd = rsqrtf(var + GEPS);
    float a = rstd * gsc[c_abs];
    float d = gbi[c_abs] - mean * a;
    Tt[n0 + 0][c_loc] = f2bu(v.x * a + d);
    Tt[n0 + 1][c_loc] = f2bu(v.y * a + d);
    Tt[n0 + 2][c_loc] = f2bu(v.z * a + d);
    Tt[n0 + 3][c_loc] = f2bu(v.w * a + d);
  }
  __syncthreads();
  int n_loc = tid >> 2, cq = (tid & 3) * 16;
  u16x8 w0 = *(const u16x8*)&Tt[n_loc][cq];
  u16x8 w1 = *(const u16x8*)&Tt[n_loc][cq + 8];
  unsigned short* dst = (unsigned short*)xt + ((size_t)(b * NHW + nB + n_loc)) * NC + cB + cq;
  *(u16x8*)dst = w0;
  *(u16x8*)(dst + 8) = w1;
}

// ---------------- MFMA GEMM (qkv): D[o][n] = W[o][:]·Bm[n][:] + bias[o] ----------------
// oB<256 -> qo [n][C]; <512 -> ko [n][C]; else vo [b][c][n]  (bf16)
// XCD swizzle: cluster consecutive nB-tiles on one XCD so each XCD's B-matrix
// working set L2-fits. Tt halved (two wy-passes) -> LDS 49.4 KB; with
// __launch_bounds__(256,3) this gives 3 blocks/CU -> 768 blocks in one round.
__global__ __launch_bounds__(256, 3)
void gemm_kernel(const bf16* __restrict__ Wb, const bf16* __restrict__ Bm,
                 const float* __restrict__ bias,
                 bf16* __restrict__ qo, bf16* __restrict__ ko, bf16* __restrict__ vo){
  // relabel: lin -> (xcd, idx); nB from xcd*gx8 + idx%gx8, oB from idx/gx8
  const int lin = blockIdx.x + gridDim.x * blockIdx.y;
  const int gx8 = gridDim.x >> 3;                 // nB tiles per XCD (=16)
  const int xcd = lin & 7, idx = lin >> 3;
  const int nB = (xcd * gx8 + (idx & (gx8 - 1))) * 128;
  const int oB = (idx / gx8) * 128;
  const int tid = threadIdx.x;
  const int wave = tid >> 6, lane = tid & 63;
  const int l15 = lane & 15, quad = lane >> 4;
  const int wx = wave & 1, wy = wave >> 1;

  __shared__ __align__(16) unsigned short Ast[2][512 * 8];
  __shared__ __align__(16) unsigned short Bst[2][512 * 8];
  __shared__ __align__(16) unsigned short Tt[64 * 136];

  const short* Wp = (const short*)Wb;
  const short* Bp = (const short*)Bm;

  f32x4 acc[4][4];
  #pragma unroll
  for(int mi = 0; mi < 4; mi++)
    #pragma unroll
    for(int ni = 0; ni < 4; ni++) acc[mi][ni] = (f32x4){0.f, 0.f, 0.f, 0.f};

  // prologue stage k0 = 0 into buf 0
  #pragma unroll
  for(int t = 0; t < 2; t++){
    int qn0 = (wave * 2 + t) * 64, qn = qn0 + lane;
    int o = qn >> 2, slot = qn & 3;
    gload_lds16(Wp + (size_t)(oB + o) * NC + ((slot ^ ((o >> 1) & 3)) * 8), &Ast[0][qn0 * 8]);
  }
  #pragma unroll
  for(int t = 0; t < 2; t++){
    int qn0 = (wave * 2 + t) * 64, qn = qn0 + lane;
    int n = qn >> 2, slot = qn & 3;
    gload_lds16(Bp + (size_t)(nB + n) * NC + ((slot ^ ((n >> 1) & 3)) * 8), &Bst[0][qn0 * 8]);
  }

  for(int kt = 0; kt < 8; kt++){
    __syncthreads();
    const int p = kt & 1;
    if(kt < 7){
      const int k0 = (kt + 1) * 32;
      #pragma unroll
      for(int t = 0; t < 2; t++){
        int qn0 = (wave * 2 + t) * 64, qn = qn0 + lane;
        int o = qn >> 2, slot = qn & 3;
        gload_lds16(Wp + (size_t)(oB + o) * NC + k0 + ((slot ^ ((o >> 1) & 3)) * 8), &Ast[p ^ 1][qn0 * 8]);
      }
      #pragma unroll
      for(int t = 0; t < 2; t++){
        int qn0 = (wave * 2 + t) * 64, qn = qn0 + lane;
        int n = qn >> 2, slot = qn & 3;
        gload_lds16(Bp + (size_t)(nB + n) * NC + k0 + ((slot ^ ((n >> 1) & 3)) * 8), &Bst[p ^ 1][qn0 * 8]);
      }
    }
    bf16x8 Af[4], Bf[4];
    #pragma unroll
    for(int mi = 0; mi < 4; mi++){
      int o = wx * 64 + mi * 16 + l15;
      Af[mi] = *(const bf16x8*)&Ast[p][(o * 4 + (quad ^ ((o >> 1) & 3))) * 8];
    }
    #pragma unroll
    for(int ni = 0; ni < 4; ni++){
      int n = wy * 64 + ni * 16 + l15;
      Bf[ni] = *(const bf16x8*)&Bst[p][(n * 4 + (quad ^ ((n >> 1) & 3))) * 8];
    }
    __builtin_amdgcn_s_setprio(1);
    #pragma unroll
    for(int mi = 0; mi < 4; mi++)
      #pragma unroll
      for(int ni = 0; ni < 4; ni++)
        acc[mi][ni] = MFMA16(Af[mi], Bf[ni], acc[mi][ni]);
    __builtin_amdgcn_s_setprio(0);
  }

  float bi[4][4];
  #pragma unroll
  for(int mi = 0; mi < 4; mi++)
    #pragma unroll
    for(int r = 0; r < 4; r++)
      bi[mi][r] = bias[oB + wx * 64 + mi * 16 + quad * 4 + r];

  if(oB >= 512){
    #pragma unroll
    for(int mi = 0; mi < 4; mi++){
      #pragma unroll
      for(int ni = 0; ni < 4; ni++){
        int na = nB + wy * 64 + ni * 16 + l15;
        #pragma unroll
        for(int r = 0; r < 4; r++){
          int c = oB - 512 + wx * 64 + mi * 16 + quad * 4 + r;
          vo[((size_t)(na >> 12) * NC + c) * NHW + (na & 4095)] = f2b(acc[mi][ni][r] + bi[mi][r]);
        }
      }
    }
  } else {
    // q/k: transpose through half-size Tt in two wy-passes, write [n][C]
    bf16* dst = (oB < 256) ? qo : ko;
    const int oc0 = oB & 255;      // 0/128 for q, 256/384 -> 0/128 for k
    #pragma unroll
    for(int hp = 0; hp < 2; hp++){
      if(hp) __syncthreads();      // protect Tt reuse across passes
      if(wy == hp){
        #pragma unroll
        for(int mi = 0; mi < 4; mi++){
          int ob = wx * 64 + mi * 16 + quad * 4;
          #pragma unroll
          for(int ni = 0; ni < 4; ni++){
            int nl = ni * 16 + l15;          // 0..63
            ushort4 pk;
            pk.x = f2bu(acc[mi][ni][0] + bi[mi][0]);
            pk.y = f2bu(acc[mi][ni][1] + bi[mi][1]);
            pk.z = f2bu(acc[mi][ni][2] + bi[mi][2]);
            pk.w = f2bu(acc[mi][ni][3] + bi[mi][3]);
            *(ushort4*)&Tt[nl * 136 + ob] = pk;
          }
        }
      }
      __syncthreads();
      int row = tid >> 2, cq = (tid & 3) * 32;
      unsigned short* gp = (unsigned short*)dst + (size_t)(nB + hp * 64 + row) * NC + oc0 + cq;
      #pragma unroll
      for(int j = 0; j < 4; j++)
        *(u16x8*)(gp + j * 8) = *(const u16x8*)&Tt[row * 136 + cq + j * 8];
    }
  }
}

// ---------------- proj GEMM with fused combine (R7 config: best measured) ----------------
// Tile 128o x 64n, grid (256,2) = 512 blocks -> 2 blocks/CU.
// R8's 64o x 64n / 4 blocks/CU variant was neutral-to-negative (proj is at its
// traffic floor, not latency-bound) -> reverted to the R7 configuration.
// B-row n = attn[n][:] = (Σ_h Opart_h[n][:]) * inv_l[n], combined in-register
// during staging; inv_l computed once in the prologue.
__global__ __launch_bounds__(256, 2)
void proj_gemm_kernel(const bf16* __restrict__ Wb, const bf16* __restrict__ Opart,
                      const float* __restrict__ lpart, const float* __restrict__ bias,
                      float* __restrict__ fo, const float* __restrict__ xres){
  const int lin = blockIdx.x + gridDim.x * blockIdx.y;
  const int gx8 = gridDim.x >> 3;                 // 32 nB-tiles (of 64) per XCD
  const int xcd = lin & 7, idx = lin >> 3;
  const int nB = (xcd * gx8 + (idx & (gx8 - 1))) * 64;
  const int oB = (idx / gx8) * 128;
  const int tid = threadIdx.x;
  const int wave = tid >> 6, lane = tid & 63;
  const int l15 = lane & 15, quad = lane >> 4;
  const int wx = wave & 1, wy = wave >> 1;
  const int HS = NB * NHW;                        // 16384 rows per quarter
  const size_t QSTRIDE = (size_t)HS * NC;         // elements per quarter

  __shared__ __align__(16) unsigned short Ast[2][512 * 8];
  __shared__ __align__(16) unsigned short Bst[2][256 * 8];

  const short* Wp = (const short*)Wb;
  const unsigned short* Op = (const unsigned short*)Opart;

  // per-lane fixed staging coords (one 256-lane slot covers the 64x32 B-tile)
  const int qn = tid;
  const int bn = qn >> 2, bsl = qn & 3;
  const int coff = (bsl ^ ((bn >> 1) & 3)) * 8;
  const int ng = nB + bn;
  const float lsum = lpart[ng] + lpart[HS + ng] + lpart[2 * HS + ng] + lpart[3 * HS + ng];
  const float inv = 1.f / lsum;
  const size_t base = (size_t)ng * NC + coff;

  f32x4 acc[4][2];
  #pragma unroll
  for(int mi = 0; mi < 4; mi++)
    #pragma unroll
    for(int ni = 0; ni < 2; ni++) acc[mi][ni] = (f32x4){0.f, 0.f, 0.f, 0.f};

  // prologue: stage kt=0 into buf 0
  #pragma unroll
  for(int t = 0; t < 2; t++){
    int qn0 = (wave * 2 + t) * 64, qq = qn0 + lane;
    int o = qq >> 2, sl = qq & 3;
    gload_lds16(Wp + (size_t)(oB + o) * NC + ((sl ^ ((o >> 1) & 3)) * 8), &Ast[0][qn0 * 8]);
  }
  {
    u16x8 a0 = *(const u16x8*)(Op + base);
    u16x8 a1 = *(const u16x8*)(Op + base + QSTRIDE);
    u16x8 a2 = *(const u16x8*)(Op + base + 2 * QSTRIDE);
    u16x8 a3 = *(const u16x8*)(Op + base + 3 * QSTRIDE);
    u16x8 o;
    #pragma unroll
    for(int e = 0; e < 8; e++)
      o[e] = f2bu((u2f(a0[e]) + u2f(a1[e]) + u2f(a2[e]) + u2f(a3[e])) * inv);
    *(u16x8*)&Bst[0][qn * 8] = o;
  }

  for(int kt = 0; kt < 8; kt++){
    __syncthreads();
    const int p = kt & 1;
    if(kt < 7){
      const int k0 = (kt + 1) * 32;
      #pragma unroll
      for(int t = 0; t < 2; t++){
        int qn0 = (wave * 2 + t) * 64, qq = qn0 + lane;
        int o = qq >> 2, sl = qq & 3;
        gload_lds16(Wp + (size_t)(oB + o) * NC + k0 + ((sl ^ ((o >> 1) & 3)) * 8), &Ast[p ^ 1][qn0 * 8]);
      }
      u16x8 a0 = *(const u16x8*)(Op + base + k0);
      u16x8 a1 = *(const u16x8*)(Op + base + k0 + QSTRIDE);
      u16x8 a2 = *(const u16x8*)(Op + base + k0 + 2 * QSTRIDE);
      u16x8 a3 = *(const u16x8*)(Op + base + k0 + 3 * QSTRIDE);
      u16x8 o;
      #pragma unroll
      for(int e = 0; e < 8; e++)
        o[e] = f2bu((u2f(a0[e]) + u2f(a1[e]) + u2f(a2[e]) + u2f(a3[e])) * inv);
      *(u16x8*)&Bst[p ^ 1][qn * 8] = o;
    }
    bf16x8 Af[4], Bf[2];
    #pragma unroll
    for(int mi = 0; mi < 4; mi++){
      int o = wx * 64 + mi * 16 + l15;
      Af[mi] = *(const bf16x8*)&Ast[p][(o * 4 + (quad ^ ((o >> 1) & 3))) * 8];
    }
    #pragma unroll
    for(int ni = 0; ni < 2; ni++){
      int n = wy * 32 + ni * 16 + l15;
      Bf[ni] = *(const bf16x8*)&Bst[p][(n * 4 + (quad ^ ((n >> 1) & 3))) * 8];
    }
    __builtin_amdgcn_s_setprio(1);
    #pragma unroll
    for(int mi = 0; mi < 4; mi++)
      #pragma unroll
      for(int ni = 0; ni < 2; ni++)
        acc[mi][ni] = MFMA16(Af[mi], Bf[ni], acc[mi][ni]);
    __builtin_amdgcn_s_setprio(0);
  }

  float bi[4][4];
  #pragma unroll
  for(int mi = 0; mi < 4; mi++)
    #pragma unroll
    for(int r = 0; r < 4; r++)
      bi[mi][r] = bias[oB + wx * 64 + mi * 16 + quad * 4 + r];

  #pragma unroll
  for(int mi = 0; mi < 4; mi++){
    #pragma unroll
    for(int ni = 0; ni < 2; ni++){
      int na = nB + wy * 32 + ni * 16 + l15;
      #pragma unroll
      for(int r = 0; r < 4; r++){
        int c = oB + wx * 64 + mi * 16 + quad * 4 + r;
        size_t idx2 = ((size_t)(na >> 12) * NC + c) * NHW + (na & 4095);
        fo[idx2] = acc[mi][ni][r] + bi[mi][r] + xres[idx2];
      }
    }
  }
}

// ---------------- MFMA flash: i=32/wave, jsplit=4, no-max softmax ----------------
// q,kt: [B][n][C] (q pre-scaled C^-0.5 * log2e)  v: [B][C][n]
// S in log2-domain, P = v_exp_f32(S) via __builtin_amdgcn_exp2f (raw instr;
// library exp2f added a denormal-handling wrapper that cost +7 µs in R6).
// XCD swizzle: 2 (b,h) pairs per XCD -> K/V working set 2MB, L2-fits.
// P redistribution (S^T D-layout -> PV A-frag) fully in-register via
// permlane32_swap + permlane16_swap (see R1 notes).
__global__ __launch_bounds__(256, 2)
void flash_mfma4_kernel(const bf16* __restrict__ qg, const bf16* __restrict__ ktg,
                        const bf16* __restrict__ vg, bf16* __restrict__ Opart,
                        float* __restrict__ lpart){
  const int lin = blockIdx.x + 32 * (blockIdx.y + 4 * blockIdx.z);
  const int xcd = lin & 7, slot = lin >> 3;       // 512 = 8 XCDs x 64 slots
  const int bh = xcd * 2 + (slot >> 5);           // 2 (b,h) pairs per XCD
  const int b = bh & 3, h = bh >> 2;
  const int i0 = (slot & 31) * 128;
  const int tid = threadIdx.x;
  const int wave = tid >> 6, lane = tid & 63;
  const int l15 = lane & 15, quad = lane >> 4;

  __shared__ __align__(16) unsigned short Kt[2][1024 * 8];   // 2 x 16 KB
  __shared__ __align__(16) unsigned short Vt[2][1024 * 8];   // 2 x 16 KB

  bf16x8 Qf[2][8];
  #pragma unroll
  for(int ist = 0; ist < 2; ist++){
    const short* qp = (const short*)qg +
        ((size_t)b * NHW + i0 + wave * 32 + ist * 16 + l15) * NC + quad * 8;
    #pragma unroll
    for(int ks = 0; ks < 8; ks++) Qf[ist][ks] = *(const bf16x8*)(qp + ks * 32);
  }

  const short* kb = (const short*)ktg + ((size_t)b * NHW + h * 1024) * NC;
  const short* vb = (const short*)vg + (size_t)b * NC * NHW + h * 1024;

  f32x4 O[2][16];
  #pragma unroll
  for(int ist = 0; ist < 2; ist++)
    #pragma unroll
    for(int ct = 0; ct < 16; ct++) O[ist][ct] = (f32x4){0.f, 0.f, 0.f, 0.f};
  float lr0 = 0.f, lr1 = 0.f;

  // prologue: stage tile 0
  #pragma unroll
  for(int t = 0; t < 4; t++){
    int qn0 = (wave * 4 + t) * 64, qn = qn0 + lane;
    int j = qn >> 5, slot2 = qn & 31;
    gload_lds16(kb + (size_t)j * NC + ((slot2 ^ (j & 7)) * 8), &Kt[0][qn0 * 8]);
  }
  #pragma unroll
  for(int t = 0; t < 4; t++){
    int qn0 = (wave * 4 + t) * 64, qn = qn0 + lane;
    int c = qn >> 2, slot2 = qn & 3;
    gload_lds16(vb + (size_t)c * NHW + ((slot2 ^ ((c >> 1) & 3)) * 8), &Vt[0][qn0 * 8]);
  }

  for(int jt = 0; jt < 32; jt++){
    __syncthreads();
    const int p = jt & 1;
    if(jt < 31){
      const int j0n = (jt + 1) * 32;
      #pragma unroll
      for(int t = 0; t < 4; t++){
        int qn0 = (wave * 4 + t) * 64, qn = qn0 + lane;
        int j = qn >> 5, slot2 = qn & 31;
        gload_lds16(kb + (size_t)(j0n + j) * NC + ((slot2 ^ (j & 7)) * 8), &Kt[p ^ 1][qn0 * 8]);
      }
      #pragma unroll
      for(int t = 0; t < 4; t++){
        int qn0 = (wave * 4 + t) * 64, qn = qn0 + lane;
        int c = qn >> 2, slot2 = qn & 3;
        gload_lds16(vb + (size_t)c * NHW + j0n + ((slot2 ^ ((c >> 1) & 3)) * 8), &Vt[p ^ 1][qn0 * 8]);
      }
    }
    // ---- S^T = K·Q^T for both i-subtiles (K-frag read once) ----
    f32x4 S[2][2];
    __builtin_amdgcn_s_setprio(1);
    #pragma unroll
    for(int st = 0; st < 2; st++){
      S[st][0] = (f32x4){0.f, 0.f, 0.f, 0.f};
      S[st][1] = (f32x4){0.f, 0.f, 0.f, 0.f};
      const int j = st * 16 + l15;
      const unsigned short* kr = &Kt[p][(size_t)j * 256];
      #pragma unroll
      for(int ks = 0; ks < 8; ks++){
        int slot2 = (ks * 4 + quad) ^ (j & 7);
        bf16x8 kf = *(const bf16x8*)&kr[slot2 * 8];
        S[st][0] = MFMA16(kf, Qf[0][ks], S[st][0]);
        S[st][1] = MFMA16(kf, Qf[1][ks], S[st][1]);
      }
    }
    __builtin_amdgcn_s_setprio(0);
    // ---- P = exp2(S); build PV A-frags fully in-register ----
    bf16x8 Pf[2];
    #pragma unroll
    for(int ist = 0; ist < 2; ist++){
      float p0 = fexp2(S[0][ist][0]), p1 = fexp2(S[0][ist][1]);
      float p2 = fexp2(S[0][ist][2]), p3 = fexp2(S[0][ist][3]);
      float p4 = fexp2(S[1][ist][0]), p5 = fexp2(S[1][ist][1]);
      float p6 = fexp2(S[1][ist][2]), p7 = fexp2(S[1][ist][3]);
      float sm = ((p0 + p1) + (p2 + p3)) + ((p4 + p5) + (p6 + p7));
      if(ist == 0) lr0 += sm; else lr1 += sm;
      unsigned A0 = pk2(p0, p1), A1 = pk2(p2, p3);
      unsigned B0 = pk2(p4, p5), B1 = pk2(p6, p7);
      auto s0 = __builtin_amdgcn_permlane32_swap(A0, B0, false, false);
      auto t0 = __builtin_amdgcn_permlane16_swap(s0[0], s0[1], false, false);
      auto s1 = __builtin_amdgcn_permlane32_swap(A1, B1, false, false);
      auto t1 = __builtin_amdgcn_permlane16_swap(s1[0], s1[1], false, false);
      union { unsigned u[4]; bf16x8 v; } w;
      w.u[0] = t0[0]; w.u[1] = t1[0]; w.u[2] = t0[1]; w.u[3] = t1[1];
      Pf[ist] = w.v;
    }
    // ---- O += P·V^T (V-frag read once, both i-subtiles) ----
    __builtin_amdgcn_s_setprio(1);
    #pragma unroll
    for(int ct = 0; ct < 16; ct++){
      int c = ct * 16 + l15;
      bf16x8 vf = *(const bf16x8*)&Vt[p][(c * 4 + (quad ^ ((c >> 1) & 3))) * 8];
      O[0][ct] = MFMA16(Pf[0], vf, O[0][ct]);
      O[1][ct] = MFMA16(Pf[1], vf, O[1][ct]);
    }
    __builtin_amdgcn_s_setprio(0);
  }

  lr0 += __shfl_xor(lr0, 16); lr0 += __shfl_xor(lr0, 32);
  lr1 += __shfl_xor(lr1, 16); lr1 += __shfl_xor(lr1, 32);

  const size_t hb = (size_t)(h * NB + b) * NHW;
  #pragma unroll
  for(int ist = 0; ist < 2; ist++){
    #pragma unroll
    for(int r = 0; r < 4; r++){
      int i = i0 + wave * 32 + ist * 16 + quad * 4 + r;
      unsigned short* od = (unsigned short*)Opart + (hb + i) * NC + l15;
      #pragma unroll
      for(int ct = 0; ct < 16; ct++) od[ct * 16] = f2bu(O[ist][ct][r]);
    }
  }
  if(lane < 16){
    lpart[hb + i0 + wave * 32 + l15]      = lr0;
    lpart[hb + i0 + wave * 32 + 16 + l15] = lr1;
  }
}

extern "C" void kernel_launch(void* const* d_in, const int* in_sizes, int n_in,
                              void* d_out, int out_size, void* d_ws, size_t ws_size,
                              hipStream_t stream){
  (void)in_sizes; (void)n_in; (void)out_size; (void)ws_size;
  const float* x        = (const float*)d_in[0];
  const float* gn_scale = (const float*)d_in[1];
  const float* gn_bias  = (const float*)d_in[2];
  const float* wq = (const float*)d_in[3];  const float* bq = (const float*)d_in[4];
  const float* wk = (const float*)d_in[5];  const float* bk = (const float*)d_in[6];
  const float* wv = (const float*)d_in[7];  const float* bv = (const float*)d_in[8];
  const float* wp = (const float*)d_in[9];  const float* bp = (const float*)d_in[10];
  float* out = (float*)d_out;

  char* ws = (char*)d_ws;
  const size_t MB = 1048576;
  float* partial = (float*)ws;                       // 4 KB (128 groups x 4 quarters x 2)
  float* bqs   = (float*)(ws + 4096);                // 3 KB
  bf16* wqkv   = (bf16*)(ws + 8192);                 // 384 KB
  bf16* wpb    = (bf16*)(ws + 8192 + 393216);        // 128 KB
  bf16* xt     = (bf16*)(ws + 1 * MB);               // 8 MB (region reserved 32 MB)
  bf16* Opart  = xt;                                 // alias: xt dead after qkv gemm
  bf16* q      = (bf16*)(ws + 33 * MB);              // 8 MB
  bf16* k      = (bf16*)(ws + 41 * MB);              // 8 MB
  bf16* v      = (bf16*)(ws + 49 * MB);              // 8 MB
  float* lpart = (float*)(ws + 57 * MB);             // 256 KB

  gn_stats_wprep_kernel<<<1536, 256, 0, stream>>>(
      x, partial, wq, wk, wv, wp, bq, bk, bv, wqkv, wpb, bqs);
  gn_prep_kernel<<<dim3(64, 4, NB), 256, 0, stream>>>(x, partial, gn_scale, gn_bias, xt);

  gemm_kernel<<<dim3(128, 6), 256, 0, stream>>>(
      wqkv, xt, bqs, q, k, v);

  flash_mfma4_kernel<<<dim3(32, NB, 4), 256, 0, stream>>>(q, k, v, Opart, lpart);

  proj_gemm_kernel<<<dim3(256, 2), 256, 0, stream>>>(
      wpb, Opart, lpart, bp, out, x);
}